// Round 10
// baseline (181.216 us; speedup 1.0000x reference)
//
#include <hip/hip_runtime.h>
#include <cstdint>
#include <math.h>

#define HH 2048
#define WW 2048
#define HWPX (HH*WW)
#define NSEG 10
#define NB 128
#define HIST_WORDS (NSEG*NB)       // 1280
#define NSHARD 8                   // hist shards (== XCD count; blockIdx&7 affinity)
#define LOWR 0.03125f
#define INV_LOWW 4096.0f           // NB / LOWR
#define BINW (LOWR/(float)NB)      // 2.441e-4

#define K1_BLOCKS 512
#define K2_BLOCKS 512              // R5-proven config (best measured: 149.9 us)
#define NTH (K2_BLOCKS*256)        // 131072 threads; HWPX/4 / NTH = 8 iters exactly

typedef float vfloat4 __attribute__((ext_vector_type(4)));

// workspace layout (32-bit words). hist shards + counter zeroed by k1 block 0
// (kernel boundary orders vs k2). Hist = device-scope integer atomicAdd into 8
// shards: commutative + shard-sum -> EXACT totals (bit-identical). The 40 float
// sums keep R5's exact ascending tree (b=0..31 per y chunk, then y=0..15).
#define WS_BMM 0                            // 1024: k1 per-block min[512], max[512]
#define WS_HIST 1024                        // NSHARD*1280 = 10240 u32
#define WS_CNT 11264                        // 1 u32: tail-block arrival counter
#define WS_ACC 11280                        // 512*40 floats: per-block seg sums
#define WS_DSEG 31760                       // 16B-aligned: 11 float4 (seg 10 = zeros)
#define WS_DMM (WS_DSEG + 44)               // dmin, dmax (published by k2 tail for k4)
#define WS_DVAL 31808                       // HWPX floats: dval staged k2 -> k4 (16.8 MB)

// Segment rule: replicates bins = linspace(dmin,dmax,11); pixel in seg s iff
// bins[s] <= v < bins[s+1]. v == dmax (== bins[10]) is in NO segment -> 10.
__device__ __forceinline__ int seg_of(float v, float dmin, float dmax, float invw) {
    int sg = (int)((v - dmin) * invw);
    sg = sg > (NSEG-1) ? (NSEG-1) : sg;
    return (v >= dmax) ? NSEG : sg;
}

// k1: per-block depth min/max -> plain stores; block 0 zeroes hist shards + counter.
__global__ __launch_bounds__(256) void k1_minmax(const float* __restrict__ depth,
                                                 uint32_t* __restrict__ wsu) {
    float* wsf = (float*)wsu;
    if (blockIdx.x == 0) {
        for (int j = threadIdx.x; j < NSHARD*HIST_WORDS; j += 256) wsu[WS_HIST + j] = 0u;
        if (threadIdx.x == 0) wsu[WS_CNT] = 0u;
    }
    int tid = blockIdx.x * 256 + threadIdx.x;
    float vmin = INFINITY, vmax = 0.0f;
    const float4* d4 = (const float4*)depth;
    for (int i = tid; i < HWPX/4; i += NTH) {
        float4 v = d4[i];
        vmin = fminf(vmin, fminf(fminf(v.x, v.y), fminf(v.z, v.w)));
        vmax = fmaxf(vmax, fmaxf(fmaxf(v.x, v.y), fmaxf(v.z, v.w)));
    }
    #pragma unroll
    for (int off = 32; off > 0; off >>= 1) {
        vmin = fminf(vmin, __shfl_down(vmin, off, 64));
        vmax = fmaxf(vmax, __shfl_down(vmax, off, 64));
    }
    __shared__ float smin[4], smax[4];
    int wid = threadIdx.x >> 6;
    if ((threadIdx.x & 63) == 0) { smin[wid] = vmin; smax[wid] = vmax; }
    __syncthreads();
    if (threadIdx.x == 0) {
        wsf[WS_BMM + blockIdx.x]             = fminf(fminf(smin[0], smin[1]), fminf(smin[2], smin[3]));
        wsf[WS_BMM + K1_BLOCKS + blockIdx.x] = fmaxf(fmaxf(smax[0], smax[1]), fmaxf(smax[2], smax[3]));
    }
}

// Each block re-reduces k1's 512+512 per-block values (4 KB, L2/L3-hot).
__device__ __forceinline__ void block_minmax(const float* wsf, float& dmin, float& dmax,
                                             float smn[4], float smx[4]) {
    float v0 = fminf(wsf[WS_BMM + threadIdx.x], wsf[WS_BMM + 256 + threadIdx.x]);
    float v1 = fmaxf(wsf[WS_BMM + K1_BLOCKS + threadIdx.x],
                     wsf[WS_BMM + K1_BLOCKS + 256 + threadIdx.x]);
    #pragma unroll
    for (int off = 32; off > 0; off >>= 1) {
        v0 = fminf(v0, __shfl_down(v0, off, 64));
        v1 = fmaxf(v1, __shfl_down(v1, off, 64));
    }
    int wid = threadIdx.x >> 6;
    if ((threadIdx.x & 63) == 0) { smn[wid] = v0; smx[wid] = v1; }
    __syncthreads();
    dmin = fminf(fminf(smn[0], smn[1]), fminf(smn[2], smn[3]));
    dmax = fmaxf(fmaxf(smx[0], smx[1]), fmaxf(smx[2], smx[3]));
}

// k2: R5's proven body (512 blocks, 8 grid-stride iters, register per-seg stats,
// LDS hist for m < LOWR, dval plain-stored for k4) + sharded hist flush + TAIL
// BLOCK: the last block to arrive (device-scope counter, release/acquire fences)
// computes the k3 stats inline — one fewer dispatch + gap. Arithmetic and all
// float orderings identical to the measured-149.9 R5 chain.
__global__ __launch_bounds__(256, 2) void k2_hist(const float* __restrict__ image,
                                                  const float* __restrict__ depth,
                                                  const float* __restrict__ mu0p,
                                                  const float* __restrict__ mu1p,
                                                  const float* __restrict__ mu2p,
                                                  uint32_t* __restrict__ wsu) {
    __shared__ uint32_t s_hist[HIST_WORDS];
    __shared__ float s_red[4][40];
    __shared__ float s_part[16][40];
    __shared__ float s_acc[40];
    __shared__ float smn[4], smx[4];
    __shared__ int s_last;
    float* wsf = (float*)wsu;
    for (int j = threadIdx.x; j < HIST_WORDS; j += 256) s_hist[j] = 0;

    float dmin, dmax;
    block_minmax(wsf, dmin, dmax, smn, smx);       // includes the needed __syncthreads
    float invw = 10.0f / (dmax - dmin);
    float mu0 = *mu0p, mu1 = *mu1p, mu2 = *mu2p;

    float c_cnt[NSEG], c_r[NSEG], c_g[NSEG], c_b[NSEG];
    #pragma unroll
    for (int s = 0; s < NSEG; ++s) { c_cnt[s]=0.f; c_r[s]=0.f; c_g[s]=0.f; c_b[s]=0.f; }

    const float4* r4 = (const float4*)image;
    const float4* g4 = (const float4*)(image + HWPX);
    const float4* b4 = (const float4*)(image + 2*HWPX);
    const float4* d4 = (const float4*)depth;
    vfloat4* dval4 = (vfloat4*)(wsf + WS_DVAL);
    int tid = blockIdx.x * 256 + threadIdx.x;
    for (int i = tid; i < HWPX/4; i += NTH) {
        float4 rv = r4[i], gv = g4[i], bv = b4[i], dv = d4[i];
        float ra[4] = {rv.x, rv.y, rv.z, rv.w};
        float ga[4] = {gv.x, gv.y, gv.z, gv.w};
        float ba[4] = {bv.x, bv.y, bv.z, bv.w};
        float da[4] = {dv.x, dv.y, dv.z, dv.w};
        float dvo[4];
        #pragma unroll
        for (int j = 0; j < 4; ++j) {
            int sg = seg_of(da[j], dmin, dmax, invw);
            float m2 = fminf(ra[j], fminf(ga[j], ba[j]));
            if (sg < NSEG && m2 < LOWR) {
                atomicAdd(&s_hist[sg*NB + (int)(m2 * INV_LOWW)], 1u);
            }
            #pragma unroll
            for (int s = 0; s < NSEG; ++s) {
                float sel = (sg == s) ? 1.0f : 0.0f;
                c_cnt[s] += sel;
                c_r[s] += sel * ra[j];
                c_g[s] += sel * ga[j];
                c_b[s] += sel * ba[j];
            }
            dvo[j] = mu0 + mu1 * fmaxf(ga[j], ba[j]) + mu2 * ra[j];
        }
        vfloat4 dq = {dvo[0], dvo[1], dvo[2], dvo[3]};
        dval4[i] = dq;                              // plain store: cache-resident for k4
    }
    #pragma unroll
    for (int s = 0; s < NSEG; ++s) {
        #pragma unroll
        for (int off = 32; off > 0; off >>= 1) {
            c_cnt[s] += __shfl_down(c_cnt[s], off, 64);
            c_r[s]   += __shfl_down(c_r[s],   off, 64);
            c_g[s]   += __shfl_down(c_g[s],   off, 64);
            c_b[s]   += __shfl_down(c_b[s],   off, 64);
        }
    }
    int wid = threadIdx.x >> 6;
    if ((threadIdx.x & 63) == 0) {
        #pragma unroll
        for (int s = 0; s < NSEG; ++s) {
            s_red[wid][s]      = c_cnt[s];
            s_red[wid][10 + s] = c_r[s];
            s_red[wid][20 + s] = c_g[s];
            s_red[wid][30 + s] = c_b[s];
        }
    }
    __syncthreads();
    // hist flush: sharded device atomics (8x less contention, XCD-affine)
    uint32_t* shard = wsu + WS_HIST + (blockIdx.x & (NSHARD-1)) * HIST_WORDS;
    for (int j = threadIdx.x; j < HIST_WORDS; j += 256) {
        uint32_t v = s_hist[j];
        if (v) atomicAdd(&shard[j], v);
    }
    if (threadIdx.x < 40) {
        float v = s_red[0][threadIdx.x] + s_red[1][threadIdx.x]
                + s_red[2][threadIdx.x] + s_red[3][threadIdx.x];
        wsf[WS_ACC + blockIdx.x*40 + threadIdx.x] = v;   // plain: L2-resident
    }

    // ---- tail-block election (release: make this block's ACC + hist visible) ----
    __threadfence();
    if (threadIdx.x == 0) {
        uint32_t old = __hip_atomic_fetch_add(&wsu[WS_CNT], 1u,
                                              __ATOMIC_ACQ_REL, __HIP_MEMORY_SCOPE_AGENT);
        s_last = (old == K2_BLOCKS - 1) ? 1 : 0;
    }
    __syncthreads();
    if (!s_last) return;
    __threadfence();                               // acquire side

    // ---- inline k3 (exactly R5's k3_stats arithmetic) ----
    // hist totals: sum 8 shards, agent-scoped loads (cross-XCD coherent).
    for (int j = threadIdx.x; j < HIST_WORDS; j += 256) {
        uint32_t acc = 0;
        #pragma unroll
        for (int c = 0; c < NSHARD; ++c)
            acc += __hip_atomic_load(&wsu[WS_HIST + c*HIST_WORDS + j],
                                     __ATOMIC_RELAXED, __HIP_MEMORY_SCOPE_AGENT);
        s_hist[j] = acc;
    }
    // 40-float reduction, R5's exact tree: partial[y][j] = sum_{b=0..31 asc}
    // acc[(y*32+b)][j]; total[j] = sum_{y=0..15 asc} partial[y][j].
    for (int q = threadIdx.x; q < 16*40; q += 256) {
        int y = q / 40, j = q - y*40;
        const uint32_t* p = wsu + WS_ACC + (size_t)(y*32)*40 + j;
        float acc = 0.0f;
        #pragma unroll
        for (int b = 0; b < 32; ++b) {
            uint32_t u = __hip_atomic_load(&p[(size_t)b*40],
                                           __ATOMIC_RELAXED, __HIP_MEMORY_SCOPE_AGENT);
            acc += __uint_as_float(u);
        }
        s_part[y][j] = acc;
    }
    __syncthreads();
    if (threadIdx.x < 40) {
        float t = 0.0f;
        #pragma unroll
        for (int y = 0; y < 16; ++y) t += s_part[y][threadIdx.x];  // ordered y ascending
        s_acc[threadIdx.x] = t;
    }
    __syncthreads();
    int s = threadIdx.x;
    if (s < NSEG) {
        float fn = s_acc[s];                   // exact integer-valued float
        uint32_t n = (uint32_t)(fn + 0.5f);
        uint32_t k = n / 100;                  // n * BOTTOM_PCT // 100
        const uint32_t* h = &s_hist[s*NB];
        float bsum = 0.0f; uint32_t taken = 0;
        for (int b = 0; b < NB; ++b) {
            uint32_t rem = k - taken;
            uint32_t c = h[b];
            uint32_t t = c < rem ? c : rem;
            bsum += (float)t * (((float)b + 0.5f) * BINW);
            taken += t;
        }
        if (taken < k) bsum += (float)(k - taken) * LOWR;
        float B = (k > 0) ? (bsum / (float)k) : 0.0f;
        wsf[WS_DSEG + s*4 + 0] = s_acc[10 + s] / fn - B;
        wsf[WS_DSEG + s*4 + 1] = s_acc[20 + s] / fn - B;
        wsf[WS_DSEG + s*4 + 2] = s_acc[30 + s] / fn - B;
        wsf[WS_DSEG + s*4 + 3] = 0.0f;
    } else if (s == NSEG) {
        wsf[WS_DSEG + 40] = 0.0f; wsf[WS_DSEG + 41] = 0.0f;
        wsf[WS_DSEG + 42] = 0.0f; wsf[WS_DSEG + 43] = 0.0f;
    } else if (s == NSEG+1) {
        wsf[WS_DMM] = dmin; wsf[WS_DMM + 1] = dmax;
    }
}

// k4: 3x3 depth-guided smoothing; reads staged dval (image never touched)
__global__ __launch_bounds__(256, 2) void k4_out(const float* __restrict__ depth,
                                                 const uint32_t* __restrict__ wsu,
                                                 float* __restrict__ out) {
    __shared__ float4 s_D4[NSEG+1];
    const float* wsf = (const float*)wsu;
    if (threadIdx.x < NSEG+1)
        s_D4[threadIdx.x] = ((const float4*)(wsf + WS_DSEG))[threadIdx.x];
    __syncthreads();

    float dmin = wsf[WS_DMM];
    float dmax = wsf[WS_DMM + 1];
    float invw = 10.0f / (dmax - dmin);

    int gid = blockIdx.x * 256 + threadIdx.x;       // one 4-px quad per thread
    int row = gid >> 9;                              // uniform per wave
    int col = (gid & 511) << 2;
    int lane = threadIdx.x & 63;

    float4 dva4 = ((const float4*)(wsf + WS_DVAL))[gid];

    float nd[3][6];
    #pragma unroll
    for (int rr = 0; rr < 3; ++rr) {
        int r2 = row + rr - 1;
        if (r2 >= 0 && r2 < HH) {                    // wave-uniform branch
            const float* dp = depth + (size_t)r2 * WW + col;
            float4 m = *(const float4*)dp;
            float left  = __shfl_up(m.w, 1, 64);
            float right = __shfl_down(m.x, 1, 64);
            if (lane == 0)  left  = (col > 0)      ? dp[-1] : INFINITY;
            if (lane == 63) right = (col + 4 < WW) ? dp[4]  : INFINITY;
            nd[rr][0] = left;  nd[rr][1] = m.x; nd[rr][2] = m.y;
            nd[rr][3] = m.z;   nd[rr][4] = m.w; nd[rr][5] = right;
        } else {
            #pragma unroll
            for (int cc = 0; cc < 6; ++cc) nd[rr][cc] = INFINITY;
        }
    }

    float cnt[4], A0[4], A1[4], A2[4];
    #pragma unroll
    for (int j = 0; j < 4; ++j) { cnt[j]=0.f; A0[j]=0.f; A1[j]=0.f; A2[j]=0.f; }

    #pragma unroll
    for (int rr = 0; rr < 3; ++rr) {
        #pragma unroll
        for (int cc = 0; cc < 6; ++cc) {
            float nv = nd[rr][cc];
            float4 dd = s_D4[seg_of(nv, dmin, dmax, invw)];
            #pragma unroll
            for (int j = 0; j < 4; ++j) {
                if (j >= cc - 2 && j <= cc) {        // compile-time folded
                    float msk = (fabsf(nv - nd[1][j+1]) < 1.0f) ? 1.0f : 0.0f;
                    cnt[j] += msk; A0[j] += msk*dd.x; A1[j] += msk*dd.y; A2[j] += msk*dd.z;
                }
            }
        }
    }

    float dva[4] = {dva4.x, dva4.y, dva4.z, dva4.w};
    float o0[4], o1[4], o2[4];
    #pragma unroll
    for (int j = 0; j < 4; ++j) {
        float rc = 1.0f / cnt[j];
        float4 Dc = s_D4[seg_of(nd[1][j+1], dmin, dmax, invw)];
        // E = F_SCALE*(P_MIX*D + (1-P_MIX)*a') = D + a'; J = E*d
        o0[j] = (Dc.x + A0[j]*rc) * dva[j];
        o1[j] = (Dc.y + A1[j]*rc) * dva[j];
        o2[j] = (Dc.z + A2[j]*rc) * dva[j];
    }
    size_t base = (size_t)row * WW + col;
    vfloat4 v0 = {o0[0], o0[1], o0[2], o0[3]};
    vfloat4 v1 = {o1[0], o1[1], o1[2], o1[3]};
    vfloat4 v2 = {o2[0], o2[1], o2[2], o2[3]};
    __builtin_nontemporal_store(v0, (vfloat4*)(out + base));
    __builtin_nontemporal_store(v1, (vfloat4*)(out + HWPX + base));
    __builtin_nontemporal_store(v2, (vfloat4*)(out + 2*HWPX + base));
}

extern "C" void kernel_launch(void* const* d_in, const int* in_sizes, int n_in,
                              void* d_out, int out_size, void* d_ws, size_t ws_size,
                              hipStream_t stream) {
    const float* image = (const float*)d_in[0];
    const float* depth = (const float*)d_in[1];
    const float* mu0   = (const float*)d_in[2];
    const float* mu1   = (const float*)d_in[3];
    const float* mu2   = (const float*)d_in[4];
    uint32_t* wsu = (uint32_t*)d_ws;
    float* out = (float*)d_out;

    hipLaunchKernelGGL(k1_minmax, dim3(K1_BLOCKS), dim3(256), 0, stream, depth, wsu);
    hipLaunchKernelGGL(k2_hist,   dim3(K2_BLOCKS), dim3(256), 0, stream,
                       image, depth, mu0, mu1, mu2, wsu);
    hipLaunchKernelGGL(k4_out,    dim3((HWPX/4)/256), dim3(256), 0, stream,
                       depth, wsu, out);
}

// Round 11
// 149.255 us; speedup vs baseline: 1.2141x; 1.2141x over previous
//
#include <hip/hip_runtime.h>
#include <cstdint>
#include <math.h>

#define HH 2048
#define WW 2048
#define HWPX (HH*WW)
#define NSEG 10
#define NB 128
#define HIST_WORDS (NSEG*NB)       // 1280
#define LOWR 0.03125f
#define INV_LOWW 4096.0f           // NB / LOWR
#define BINW (LOWR/(float)NB)      // 2.441e-4

#define K1_BLOCKS 512
#define K2_BLOCKS 512              // best-measured config (R5: 149.9 us)
#define NTH (K2_BLOCKS*256)        // 131072 threads; HWPX/4 / NTH = 8 iters exactly

typedef float vfloat4 __attribute__((ext_vector_type(4)));

// workspace layout (32-bit words) — hist is zeroed by k1 block 0 (kernel-boundary
// ordering guarantees visibility to k2); everything else written before read.
// Histogram accumulation is device-scope integer atomicAdd: commutative, EXACT.
// The 40 floats keep their exact ordered tree (b=0..31 per y, then y=0..15) in k3.
#define WS_BMM 0                            // 1024: k1 per-block min[512], max[512]
#define WS_HIST 1024                        // 1280 u32: global histogram (atomics)
#define WS_ACC 2304                         // 512*40 floats: per-block seg sums
#define WS_DSEG 22784                       // 16B-aligned: 11 float4 (seg 10 = zeros)
#define WS_DMM (WS_DSEG + 44)               // dmin, dmax (published by k3 for k4)
#define WS_DVAL 22832                       // HWPX floats: dval staged k2 -> k4 (16.8 MB)

// Segment rule: replicates bins = linspace(dmin,dmax,11); pixel in seg s iff
// bins[s] <= v < bins[s+1]. v == dmax (== bins[10]) is in NO segment -> 10.
__device__ __forceinline__ int seg_of(float v, float dmin, float dmax, float invw) {
    int sg = (int)((v - dmin) * invw);
    sg = sg > (NSEG-1) ? (NSEG-1) : sg;
    return (v >= dmax) ? NSEG : sg;
}

// k1: per-block depth min/max -> plain stores; block 0 also zeroes the hist.
__global__ __launch_bounds__(256) void k1_minmax(const float* __restrict__ depth,
                                                 uint32_t* __restrict__ wsu) {
    float* wsf = (float*)wsu;
    if (blockIdx.x == 0) {
        for (int j = threadIdx.x; j < HIST_WORDS; j += 256) wsu[WS_HIST + j] = 0u;
    }
    int tid = blockIdx.x * 256 + threadIdx.x;
    float vmin = INFINITY, vmax = 0.0f;
    const float4* d4 = (const float4*)depth;
    for (int i = tid; i < HWPX/4; i += NTH) {
        float4 v = d4[i];
        vmin = fminf(vmin, fminf(fminf(v.x, v.y), fminf(v.z, v.w)));
        vmax = fmaxf(vmax, fmaxf(fmaxf(v.x, v.y), fmaxf(v.z, v.w)));
    }
    #pragma unroll
    for (int off = 32; off > 0; off >>= 1) {
        vmin = fminf(vmin, __shfl_down(vmin, off, 64));
        vmax = fmaxf(vmax, __shfl_down(vmax, off, 64));
    }
    __shared__ float smin[4], smax[4];
    int wid = threadIdx.x >> 6;
    if ((threadIdx.x & 63) == 0) { smin[wid] = vmin; smax[wid] = vmax; }
    __syncthreads();
    if (threadIdx.x == 0) {
        wsf[WS_BMM + blockIdx.x]             = fminf(fminf(smin[0], smin[1]), fminf(smin[2], smin[3]));
        wsf[WS_BMM + K1_BLOCKS + blockIdx.x] = fmaxf(fmaxf(smax[0], smax[1]), fmaxf(smax[2], smax[3]));
    }
}

// Each block re-reduces k1's 512+512 per-block values (4 KB, L2/L3-hot).
__device__ __forceinline__ void block_minmax(const float* wsf, float& dmin, float& dmax,
                                             float smn[4], float smx[4]) {
    float v0 = fminf(wsf[WS_BMM + threadIdx.x], wsf[WS_BMM + 256 + threadIdx.x]);
    float v1 = fmaxf(wsf[WS_BMM + K1_BLOCKS + threadIdx.x],
                     wsf[WS_BMM + K1_BLOCKS + 256 + threadIdx.x]);
    #pragma unroll
    for (int off = 32; off > 0; off >>= 1) {
        v0 = fminf(v0, __shfl_down(v0, off, 64));
        v1 = fmaxf(v1, __shfl_down(v1, off, 64));
    }
    int wid = threadIdx.x >> 6;
    if ((threadIdx.x & 63) == 0) { smn[wid] = v0; smx[wid] = v1; }
    __syncthreads();
    dmin = fminf(fminf(smn[0], smn[1]), fminf(smn[2], smn[3]));
    dmax = fmaxf(fmaxf(smx[0], smx[1]), fmaxf(smx[2], smx[3]));
}

// k2: register per-seg stats; LDS hist only for m < LOWR (~9%); dval staged
// (plain store — stays cache-resident for k4). Depth-1 prefetch pipeline:
// k2 is frozen at 2 blocks/CU, so latency hiding comes from ILP.
// Hist flush: device atomicAdd (exact). Acc flush: 40 floats to WS_ACC.
__global__ __launch_bounds__(256, 2) void k2_hist(const float* __restrict__ image,
                                                  const float* __restrict__ depth,
                                                  const float* __restrict__ mu0p,
                                                  const float* __restrict__ mu1p,
                                                  const float* __restrict__ mu2p,
                                                  uint32_t* __restrict__ wsu) {
    __shared__ uint32_t s_hist[HIST_WORDS];
    __shared__ float s_red[4][40];
    __shared__ float smn[4], smx[4];
    float* wsf = (float*)wsu;
    for (int j = threadIdx.x; j < HIST_WORDS; j += 256) s_hist[j] = 0;

    float dmin, dmax;
    block_minmax(wsf, dmin, dmax, smn, smx);       // includes the needed __syncthreads
    float invw = 10.0f / (dmax - dmin);
    float mu0 = *mu0p, mu1 = *mu1p, mu2 = *mu2p;

    float c_cnt[NSEG], c_r[NSEG], c_g[NSEG], c_b[NSEG];
    #pragma unroll
    for (int s = 0; s < NSEG; ++s) { c_cnt[s]=0.f; c_r[s]=0.f; c_g[s]=0.f; c_b[s]=0.f; }

    const float4* r4 = (const float4*)image;
    const float4* g4 = (const float4*)(image + HWPX);
    const float4* b4 = (const float4*)(image + 2*HWPX);
    const float4* d4 = (const float4*)depth;
    vfloat4* dval4 = (vfloat4*)(wsf + WS_DVAL);
    int tid = blockIdx.x * 256 + threadIdx.x;

    // exactly 8 grid-stride iterations; prefetch-1 software pipeline.
    float4 rv = r4[tid], gv = g4[tid], bv = b4[tid], dv = d4[tid];
    #pragma unroll 2
    for (int m = 0; m < 8; ++m) {
        int i = tid + m*NTH;
        float4 rn, gn, bn, dn;
        if (m < 7) {
            int inx = i + NTH;
            rn = r4[inx]; gn = g4[inx]; bn = b4[inx]; dn = d4[inx];
        }
        float ra[4] = {rv.x, rv.y, rv.z, rv.w};
        float ga[4] = {gv.x, gv.y, gv.z, gv.w};
        float ba[4] = {bv.x, bv.y, bv.z, bv.w};
        float da[4] = {dv.x, dv.y, dv.z, dv.w};
        float dvo[4];
        #pragma unroll
        for (int j = 0; j < 4; ++j) {
            int sg = seg_of(da[j], dmin, dmax, invw);
            float m2 = fminf(ra[j], fminf(ga[j], ba[j]));
            if (sg < NSEG && m2 < LOWR) {
                atomicAdd(&s_hist[sg*NB + (int)(m2 * INV_LOWW)], 1u);
            }
            #pragma unroll
            for (int s = 0; s < NSEG; ++s) {
                float sel = (sg == s) ? 1.0f : 0.0f;
                c_cnt[s] += sel;
                c_r[s] += sel * ra[j];
                c_g[s] += sel * ga[j];
                c_b[s] += sel * ba[j];
            }
            dvo[j] = mu0 + mu1 * fmaxf(ga[j], ba[j]) + mu2 * ra[j];
        }
        vfloat4 dq = {dvo[0], dvo[1], dvo[2], dvo[3]};
        dval4[i] = dq;                              // plain store: cache-resident for k4
        rv = rn; gv = gn; bv = bn; dv = dn;
    }
    #pragma unroll
    for (int s = 0; s < NSEG; ++s) {
        #pragma unroll
        for (int off = 32; off > 0; off >>= 1) {
            c_cnt[s] += __shfl_down(c_cnt[s], off, 64);
            c_r[s]   += __shfl_down(c_r[s],   off, 64);
            c_g[s]   += __shfl_down(c_g[s],   off, 64);
            c_b[s]   += __shfl_down(c_b[s],   off, 64);
        }
    }
    int wid = threadIdx.x >> 6;
    if ((threadIdx.x & 63) == 0) {
        #pragma unroll
        for (int s = 0; s < NSEG; ++s) {
            s_red[wid][s]      = c_cnt[s];
            s_red[wid][10 + s] = c_r[s];
            s_red[wid][20 + s] = c_g[s];
            s_red[wid][30 + s] = c_b[s];
        }
    }
    __syncthreads();
    // hist: device-wide exact integer accumulation (skip empty bins)
    for (int j = threadIdx.x; j < HIST_WORDS; j += 256) {
        uint32_t v = s_hist[j];
        if (v) atomicAdd(&wsu[WS_HIST + j], v);
    }
    if (threadIdx.x < 40) {
        float v = s_red[0][threadIdx.x] + s_red[1][threadIdx.x]
                + s_red[2][threadIdx.x] + s_red[3][threadIdx.x];
        __builtin_nontemporal_store(v, &wsf[WS_ACC + blockIdx.x*40 + threadIdx.x]);
    }
}

// k3: merged stats (1 block). Hist read directly (atomics already summed).
// 40-float reduction reproduces the old tree EXACTLY: partial[y][j] =
// sum_{b=0..31 asc} acc[(y*32+b)][j]; total[j] = sum_{y=0..15 asc} partial[y][j].
__global__ void k3_stats(uint32_t* __restrict__ wsu) {
    __shared__ uint32_t s_hist[HIST_WORDS];
    __shared__ float s_part[16][40];
    __shared__ float s_acc[40];
    __shared__ float smn[4], smx[4];
    float* wsf = (float*)wsu;
    for (int j = threadIdx.x; j < HIST_WORDS; j += 256) s_hist[j] = wsu[WS_HIST + j];
    for (int q = threadIdx.x; q < 16*40; q += 256) {
        int y = q / 40, j = q - y*40;
        const float* p = wsf + WS_ACC + (size_t)(y*32)*40 + j;
        float acc = 0.0f;
        #pragma unroll
        for (int b = 0; b < 32; ++b) acc += p[b*40];   // ordered b ascending
        s_part[y][j] = acc;
    }
    float dmin, dmax;
    block_minmax(wsf, dmin, dmax, smn, smx);   // syncthreads inside covers s_hist/s_part
    if (threadIdx.x < 40) {
        float t = 0.0f;
        #pragma unroll
        for (int y = 0; y < 16; ++y) t += s_part[y][threadIdx.x];  // ordered y ascending
        s_acc[threadIdx.x] = t;
    }
    __syncthreads();
    int s = threadIdx.x;
    if (s < NSEG) {
        float fn = s_acc[s];                   // exact integer-valued float
        uint32_t n = (uint32_t)(fn + 0.5f);
        uint32_t k = n / 100;                  // n * BOTTOM_PCT // 100
        const uint32_t* h = &s_hist[s*NB];
        float bsum = 0.0f; uint32_t taken = 0;
        for (int b = 0; b < NB; ++b) {
            uint32_t rem = k - taken;
            uint32_t c = h[b];
            uint32_t t = c < rem ? c : rem;
            bsum += (float)t * (((float)b + 0.5f) * BINW);
            taken += t;
        }
        if (taken < k) bsum += (float)(k - taken) * LOWR;
        float B = (k > 0) ? (bsum / (float)k) : 0.0f;
        wsf[WS_DSEG + s*4 + 0] = s_acc[10 + s] / fn - B;
        wsf[WS_DSEG + s*4 + 1] = s_acc[20 + s] / fn - B;
        wsf[WS_DSEG + s*4 + 2] = s_acc[30 + s] / fn - B;
        wsf[WS_DSEG + s*4 + 3] = 0.0f;
    } else if (s == NSEG) {
        wsf[WS_DSEG + 40] = 0.0f; wsf[WS_DSEG + 41] = 0.0f;
        wsf[WS_DSEG + 42] = 0.0f; wsf[WS_DSEG + 43] = 0.0f;
    } else if (s == NSEG+1) {
        wsf[WS_DMM] = dmin; wsf[WS_DMM + 1] = dmax;
    }
}

// k4: 3x3 depth-guided smoothing; reads staged dval (image never touched)
__global__ __launch_bounds__(256, 2) void k4_out(const float* __restrict__ depth,
                                                 const uint32_t* __restrict__ wsu,
                                                 float* __restrict__ out) {
    __shared__ float4 s_D4[NSEG+1];
    const float* wsf = (const float*)wsu;
    if (threadIdx.x < NSEG+1)
        s_D4[threadIdx.x] = ((const float4*)(wsf + WS_DSEG))[threadIdx.x];
    __syncthreads();

    float dmin = wsf[WS_DMM];
    float dmax = wsf[WS_DMM + 1];
    float invw = 10.0f / (dmax - dmin);

    int gid = blockIdx.x * 256 + threadIdx.x;       // one 4-px quad per thread
    int row = gid >> 9;                              // uniform per wave
    int col = (gid & 511) << 2;
    int lane = threadIdx.x & 63;

    float4 dva4 = ((const float4*)(wsf + WS_DVAL))[gid];

    float nd[3][6];
    #pragma unroll
    for (int rr = 0; rr < 3; ++rr) {
        int r2 = row + rr - 1;
        if (r2 >= 0 && r2 < HH) {                    // wave-uniform branch
            const float* dp = depth + (size_t)r2 * WW + col;
            float4 m = *(const float4*)dp;
            float left  = __shfl_up(m.w, 1, 64);
            float right = __shfl_down(m.x, 1, 64);
            if (lane == 0)  left  = (col > 0)      ? dp[-1] : INFINITY;
            if (lane == 63) right = (col + 4 < WW) ? dp[4]  : INFINITY;
            nd[rr][0] = left;  nd[rr][1] = m.x; nd[rr][2] = m.y;
            nd[rr][3] = m.z;   nd[rr][4] = m.w; nd[rr][5] = right;
        } else {
            #pragma unroll
            for (int cc = 0; cc < 6; ++cc) nd[rr][cc] = INFINITY;
        }
    }

    float cnt[4], A0[4], A1[4], A2[4];
    #pragma unroll
    for (int j = 0; j < 4; ++j) { cnt[j]=0.f; A0[j]=0.f; A1[j]=0.f; A2[j]=0.f; }

    #pragma unroll
    for (int rr = 0; rr < 3; ++rr) {
        #pragma unroll
        for (int cc = 0; cc < 6; ++cc) {
            float nv = nd[rr][cc];
            float4 dd = s_D4[seg_of(nv, dmin, dmax, invw)];
            #pragma unroll
            for (int j = 0; j < 4; ++j) {
                if (j >= cc - 2 && j <= cc) {        // compile-time folded
                    float msk = (fabsf(nv - nd[1][j+1]) < 1.0f) ? 1.0f : 0.0f;
                    cnt[j] += msk; A0[j] += msk*dd.x; A1[j] += msk*dd.y; A2[j] += msk*dd.z;
                }
            }
        }
    }

    float dva[4] = {dva4.x, dva4.y, dva4.z, dva4.w};
    float o0[4], o1[4], o2[4];
    #pragma unroll
    for (int j = 0; j < 4; ++j) {
        float rc = 1.0f / cnt[j];
        float4 Dc = s_D4[seg_of(nd[1][j+1], dmin, dmax, invw)];
        // E = F_SCALE*(P_MIX*D + (1-P_MIX)*a') = D + a'; J = E*d
        o0[j] = (Dc.x + A0[j]*rc) * dva[j];
        o1[j] = (Dc.y + A1[j]*rc) * dva[j];
        o2[j] = (Dc.z + A2[j]*rc) * dva[j];
    }
    size_t base = (size_t)row * WW + col;
    vfloat4 v0 = {o0[0], o0[1], o0[2], o0[3]};
    vfloat4 v1 = {o1[0], o1[1], o1[2], o1[3]};
    vfloat4 v2 = {o2[0], o2[1], o2[2], o2[3]};
    __builtin_nontemporal_store(v0, (vfloat4*)(out + base));
    __builtin_nontemporal_store(v1, (vfloat4*)(out + HWPX + base));
    __builtin_nontemporal_store(v2, (vfloat4*)(out + 2*HWPX + base));
}

extern "C" void kernel_launch(void* const* d_in, const int* in_sizes, int n_in,
                              void* d_out, int out_size, void* d_ws, size_t ws_size,
                              hipStream_t stream) {
    const float* image = (const float*)d_in[0];
    const float* depth = (const float*)d_in[1];
    const float* mu0   = (const float*)d_in[2];
    const float* mu1   = (const float*)d_in[3];
    const float* mu2   = (const float*)d_in[4];
    uint32_t* wsu = (uint32_t*)d_ws;
    float* out = (float*)d_out;

    hipLaunchKernelGGL(k1_minmax, dim3(K1_BLOCKS), dim3(256), 0, stream, depth, wsu);
    hipLaunchKernelGGL(k2_hist,   dim3(K2_BLOCKS), dim3(256), 0, stream,
                       image, depth, mu0, mu1, mu2, wsu);
    hipLaunchKernelGGL(k3_stats,  dim3(1),         dim3(256), 0, stream, wsu);
    hipLaunchKernelGGL(k4_out,    dim3((HWPX/4)/256), dim3(256), 0, stream,
                       depth, wsu, out);
}